// Round 9
// baseline (181.780 us; speedup 1.0000x reference)
//
#include <hip/hip_runtime.h>
#include <hip/hip_bf16.h>
#include <hip/hip_fp16.h>

#define BATCH_N 256
#define IN_F    16384
#define OUT_F   16384
#define CAP     128              // edge slots per row (mean 61, 8.6 sigma margin)
#define NBUCK   256              // coarse buckets: row >> 6, 64 rows each
#define CAPB    6656             // bucket staging capacity (mean 3906 + pads + margin)
#define EPB     16384            // edges per partition block (62 blocks -> short atomic chains)
#define TBLK    1024             // transpose blocks inside fused prep kernel
#define SENT    0xFFFFFFFFu      // staging pad sentinel

typedef unsigned int u32x4 __attribute__((ext_vector_type(4)));

// ---------------- fused prep: transpose_x (blocks 0..1023) + partition ----------------
// staging record: x = (row<<14)|col  (SENT for pads), y = fp32 bits of val
// Partition is two-pass within the block: hist rows -> one padded reservation
// per (block,bucket) -> scatter. 62 blocks => 62-deep gcursor atomic chains.

__global__ void prep_kernel(const float* __restrict__ x,
                            __hip_bfloat16* __restrict__ xTh,
                            const int* __restrict__ rows,
                            const int* __restrict__ cols,
                            const float* __restrict__ vals, int nnz,
                            int* __restrict__ gcursor,
                            uint2* __restrict__ staging) {
    __shared__ int smem[64 * 65];
    int t = threadIdx.x;
    if (blockIdx.x < TBLK) {
        // ---- transpose + bf16 quantize: x [256][IN] -> xTh [2][IN][128] ----
        float* tile = (float*)smem;        // [64][65]
        int bid = blockIdx.x;
        int i0 = (bid & 255) * 64;
        int b0 = (bid >> 8) * 64;
        int tx = t & 63, ty = t >> 6;
#pragma unroll
        for (int k = 0; k < 64; k += 4)
            tile[(ty + k) * 65 + tx] = x[(size_t)(b0 + ty + k) * IN_F + i0 + tx];
        __syncthreads();
        int h = b0 >> 7, j0 = b0 & 127;
#pragma unroll
        for (int k = 0; k < 64; k += 4) {
            int col = i0 + ty + k;
            xTh[((size_t)h * IN_F + col) * 128 + j0 + tx] =
                __float2bfloat16(tile[tx * 65 + ty + k]);
        }
    } else {
        // ---- partition edges into 256 coarse buckets, line-aligned runs ----
        int* hist = smem;
        int* base = smem + NBUCK;
        hist[t] = 0;
        __syncthreads();
        int i0 = (blockIdx.x - TBLK) * EPB;
        int iend = i0 + EPB < nnz ? i0 + EPB : nnz;
        // pass 1: histogram rows only
        for (int i = i0 + t; i < iend; i += 256)
            atomicAdd(&hist[rows[i] >> 6], 1);
        __syncthreads();
        int hcnt = hist[t];
        int padded = (hcnt + 7) & ~7;          // 64 B granularity
        base[t] = (padded > 0) ? atomicAdd(&gcursor[t], padded) : 0;
        __syncthreads();
        hist[t] = 0;
        __syncthreads();
        // pass 2: scatter records
        for (int i = i0 + t; i < iend; i += 256) {
            int r = rows[i], c = cols[i];
            int bk = r >> 6;
            int p = base[bk] + atomicAdd(&hist[bk], 1);
            if (p < CAPB)
                staging[(size_t)bk * CAPB + p] =
                    make_uint2(((unsigned int)r << 14) | (unsigned int)c,
                               __float_as_uint(vals[i]));
        }
        __syncthreads();
        // sentinel-pad the tail of this block's runs
        for (int p = hcnt; p < padded; ++p) {
            int idx = base[t] + p;
            if (idx < CAPB)
                staging[(size_t)t * CAPB + idx] = make_uint2(SENT, 0u);
        }
    }
}

// ---------------- phase B: within-bucket scatter to per-row bins ----------------
// Output record (4 B): (col << 16) | fp16(val). Row implied by bin.

__global__ void bucket_scatter_kernel(const uint2* __restrict__ staging,
                                      const int* __restrict__ gcursor,
                                      unsigned int* __restrict__ edges, // [OUT][CAP]
                                      int* __restrict__ counts) {
    __shared__ int lcnt[64];
    __shared__ unsigned int lbin[64 * CAP];   // 32 KB
    int b = blockIdx.x;
    int t = threadIdx.x;
    if (t < 64) lcnt[t] = 0;
    __syncthreads();
    int n = gcursor[b];                 // multiple of 8 (padded reservations)
    if (n > CAPB) n = CAPB;
    const u32x4* st4 = (const u32x4*)(staging + (size_t)b * CAPB);
    for (int i = t; i < n / 2; i += 256) {
        u32x4 rr = __builtin_nontemporal_load(st4 + i);   // two records
#pragma unroll
        for (int q = 0; q < 2; ++q) {
            unsigned int key = q ? rr.z : rr.x;
            unsigned int vbits = q ? rr.w : rr.y;
            if (key != SENT) {
                int rl = (key >> 14) & 63;
                int p = atomicAdd(&lcnt[rl], 1);
                if (p < CAP) {
                    unsigned int col = key & 16383u;
                    __half hv = __float2half(__uint_as_float(vbits));
                    lbin[rl * CAP + p] =
                        (col << 16) | (unsigned int)__half_as_ushort(hv);
                }
            }
        }
    }
    __syncthreads();
    if (t < 64) {
        int c = lcnt[t];
        if (c > CAP) c = CAP;
        counts[b * 64 + t] = (c + 7) & ~7;
    }
    unsigned int* dst = edges + (size_t)b * 64 * CAP;
    for (int i4 = t; i4 < 64 * CAP / 4; i4 += 256) {
        int i = i4 * 4;
        int row = i >> 7;            // CAP = 128
        int slot = i & (CAP - 1);
        int c = lcnt[row];
        if (c > CAP) c = CAP;
        int lim = (c + 15) & ~15;    // 64 B line granularity
        if (slot < lim) {
            u32x4 v;
            v.x = (slot + 0 < c) ? lbin[i + 0] : 0u;
            v.y = (slot + 1 < c) ? lbin[i + 1] : 0u;
            v.z = (slot + 2 < c) ? lbin[i + 2] : 0u;
            v.w = (slot + 3 < c) ? lbin[i + 3] : 0u;
            __builtin_nontemporal_store(v, (u32x4*)(dst + i));
        }
    }
}

// ---------------- fused accumulate: both halves in one dispatch ----------------
// h = blockIdx & 1 (round-robin XCD dispatch keeps one 4 MB xh half per XCD L2).
// Edge list is wave-uniform (s_load); gather base address is scalar math.

__global__ void accum_kernel(const unsigned int* __restrict__ xh0, // [2][IN][64] bf162
                             const unsigned int* __restrict__ edges, // [OUT][CAP]
                             const int*   __restrict__ counts,    // multiple of 8
                             const float* __restrict__ bias,
                             float* __restrict__ outT) {           // [OUT][256]
    int blk = blockIdx.x;
    int h = blk & 1;
    int o = __builtin_amdgcn_readfirstlane(
        (int)((blk >> 1) * 4 + (threadIdx.x >> 6)));
    int t = threadIdx.x & 63;
    const unsigned int* xh = xh0 + (size_t)h * IN_F * 64;
    int n = counts[o];                 // uniform
    const unsigned int* el = edges + (size_t)o * CAP;
    float ax = 0.f, ay = 0.f;
    for (int j = 0; j < n; j += 8) {
        unsigned int e[8];
#pragma unroll
        for (int k = 0; k < 8; ++k) e[k] = el[j + k];     // uniform -> s_load
        unsigned int g[8];
#pragma unroll
        for (int k = 0; k < 8; ++k) {
            const unsigned int* p = xh + ((e[k] >> 16) << 6);  // scalar base
            g[k] = p[t];                                       // vgpr offset t
        }
#pragma unroll
        for (int k = 0; k < 8; ++k) {
            float v = __half2float(__ushort_as_half((unsigned short)(e[k] & 0xffffu)));
            ax += __uint_as_float(g[k] << 16) * v;
            ay += __uint_as_float(g[k] & 0xffff0000u) * v;
        }
    }
    float bv = bias[o];
    unsigned long long w = ((unsigned long long)__float_as_uint(ay + bv) << 32)
                         | __float_as_uint(ax + bv);
    __builtin_nontemporal_store(w,
        (unsigned long long*)(outT + (size_t)o * 256 + h * 128 + 2 * t));
}

// ---------------- outT [OUT][256] -> out [256][OUT] ----------------

__global__ void transpose_out_kernel(const float* __restrict__ outT,
                                     float* __restrict__ out) {
    __shared__ float tile[64][65];
    int o0 = blockIdx.x * 64;
    int b0 = blockIdx.y * 64;
    int tx = threadIdx.x & 63;
    int ty = threadIdx.x >> 6;
#pragma unroll
    for (int k = 0; k < 64; k += 4)
        tile[ty + k][tx] =
            __builtin_nontemporal_load(&outT[(size_t)(o0 + ty + k) * BATCH_N + (b0 + tx)]);
    __syncthreads();
#pragma unroll
    for (int k = 0; k < 64; k += 4)
        __builtin_nontemporal_store(tile[tx][ty + k],
            &out[(size_t)(b0 + ty + k) * OUT_F + (o0 + tx)]);
}

extern "C" void kernel_launch(void* const* d_in, const int* in_sizes, int n_in,
                              void* d_out, int out_size, void* d_ws, size_t ws_size,
                              hipStream_t stream) {
    const float* x     = (const float*)d_in[0];
    const float* wvals = (const float*)d_in[1];
    const float* bias  = (const float*)d_in[2];
    const int*   rows  = (const int*)d_in[3];
    const int*   cols  = (const int*)d_in[4];
    float* out = (float*)d_out;
    int nnz = in_sizes[1];

    const size_t MB = 1024 * 1024;
    char* ws = (char*)d_ws;
    __hip_bfloat16* xTh = (__hip_bfloat16*)(ws);        // [0, 8 MB): [2][IN][128] bf16
    float* outT    = (float*)(ws + 8 * MB);             // [8, 24 MB): [OUT][256] fp32
    uint2* staging = (uint2*)(ws + 8 * MB);             // aliases outT (13.6 MB, disjoint in time)
    unsigned int* edges = (unsigned int*)(ws + 24 * MB);// [24, 32 MB): [OUT][CAP] u32
    int*   gcursor = (int*)(ws + 32 * MB);              // 1 KB
    int*   counts  = (int*)(ws + 32 * MB + 4096);       // 64 KB

    hipMemsetAsync(gcursor, 0, NBUCK * sizeof(int), stream);

    int npart = (nnz + EPB - 1) / EPB;
    prep_kernel<<<TBLK + npart, 256, 0, stream>>>(x, xTh, rows, cols, wvals, nnz,
                                                  gcursor, staging);
    bucket_scatter_kernel<<<NBUCK, 256, 0, stream>>>(staging, gcursor, edges, counts);
    accum_kernel<<<OUT_F / 2, 256, 0, stream>>>((const unsigned int*)xTh, edges,
                                                counts, bias, outT);
    transpose_out_kernel<<<dim3(OUT_F / 64, BATCH_N / 64), 256, 0, stream>>>(outT, out);
}

// Round 10
// 171.592 us; speedup vs baseline: 1.0594x; 1.0594x over previous
//
#include <hip/hip_runtime.h>
#include <hip/hip_bf16.h>
#include <hip/hip_fp16.h>

#define BATCH_N 256
#define IN_F    16384
#define OUT_F   16384
#define CAP     128              // edge slots per row (mean 61, 8.6 sigma margin)
#define NBUCK   256              // coarse buckets: row >> 6, 64 rows each
#define CAPB    6656             // bucket staging capacity (mean ~5500 padded + margin)
#define EPB     2048             // edges per partition block (489 blocks)
#define TBLK    1024             // transpose blocks inside fused prep kernel
#define SENT    0xFFFFFFFFu     // staging pad sentinel

typedef unsigned int u32x4 __attribute__((ext_vector_type(4)));

// ---------------- fused prep: transpose_x (blocks 0..1023) + partition ----------------
// staging record: x = (row<<14)|col  (SENT for pads), y = fp32 bits of val
// Per-(block,bucket) reservations rounded to 8 records = 64 B lines.

__global__ void prep_kernel(const float* __restrict__ x,
                            __hip_bfloat16* __restrict__ xTh,
                            const int* __restrict__ rows,
                            const int* __restrict__ cols,
                            const float* __restrict__ vals, int nnz,
                            int* __restrict__ gcursor,
                            uint2* __restrict__ staging) {
    __shared__ int smem[64 * 65];
    int t = threadIdx.x;
    if (blockIdx.x < TBLK) {
        // ---- transpose + bf16 quantize: x [256][IN] -> xTh [2][IN][128] ----
        float* tile = (float*)smem;        // [64][65]
        int bid = blockIdx.x;
        int i0 = (bid & 255) * 64;
        int b0 = (bid >> 8) * 64;
        int tx = t & 63, ty = t >> 6;
#pragma unroll
        for (int k = 0; k < 64; k += 4)
            tile[(ty + k) * 65 + tx] = x[(size_t)(b0 + ty + k) * IN_F + i0 + tx];
        __syncthreads();
        int h = b0 >> 7, j0 = b0 & 127;
#pragma unroll
        for (int k = 0; k < 64; k += 4) {
            int col = i0 + ty + k;
            xTh[((size_t)h * IN_F + col) * 128 + j0 + tx] =
                __float2bfloat16(tile[tx * 65 + ty + k]);
        }
    } else {
        // ---- partition 2048 edges into 256 coarse buckets ----
        int* hist = smem;
        int* base = smem + NBUCK;
        hist[t] = 0;
        __syncthreads();
        int i0 = (blockIdx.x - TBLK) * EPB;
        unsigned int pack[8], vb[8];
        int bk[8];
#pragma unroll
        for (int k = 0; k < 8; ++k) {
            int i = i0 + k * 256 + t;
            if (i < nnz) {
                int r = rows[i], c = cols[i];
                pack[k] = ((unsigned int)r << 14) | (unsigned int)c;
                vb[k] = __float_as_uint(vals[i]);
                bk[k] = r >> 6;
                atomicAdd(&hist[bk[k]], 1);
            } else bk[k] = -1;
        }
        __syncthreads();
        int hcnt = hist[t];
        int padded = (hcnt + 7) & ~7;          // 64 B granularity
        base[t] = (padded > 0) ? atomicAdd(&gcursor[t], padded) : 0;
        __syncthreads();
        hist[t] = 0;
        __syncthreads();
#pragma unroll
        for (int k = 0; k < 8; ++k) {
            if (bk[k] >= 0) {
                int p = base[bk[k]] + atomicAdd(&hist[bk[k]], 1);
                if (p < CAPB)
                    staging[(size_t)bk[k] * CAPB + p] = make_uint2(pack[k], vb[k]);
            }
        }
        __syncthreads();
        // sentinel-pad the tail of this block's run
        for (int p = hcnt; p < padded; ++p) {
            int idx = base[t] + p;
            if (idx < CAPB)
                staging[(size_t)t * CAPB + idx] = make_uint2(SENT, 0u);
        }
    }
}

// ---------------- fused bin + accumulate ----------------
// 512 blocks: bucket = blk>>1, h = blk&1 (parity -> one 4 MB xh half per XCD).
// Block bins its staging bucket into LDS (4 B records: col<<16 | fp16(val)),
// then 4 waves x 16 rows each: edge quads via uniform ds_read_b128, broadcast
// to SGPRs with readfirstlane; gathers scalar-addressed; fp32 accumulate.

__global__ void accum_kernel(const unsigned int* __restrict__ xh0, // [2][IN][64] bf162
                             const uint2* __restrict__ staging,
                             const int*   __restrict__ gcursor,
                             const float* __restrict__ bias,
                             float* __restrict__ outT) {           // [OUT][256]
    __shared__ int lcnt[64];
    __shared__ unsigned int lbin[64 * CAP];   // 32 KB
    int blk = blockIdx.x;
    int b = blk >> 1;
    int h = blk & 1;
    int t = threadIdx.x;
    if (t < 64) lcnt[t] = 0;
    __syncthreads();
    int n = gcursor[b];                 // multiple of 8
    if (n > CAPB) n = CAPB;
    const u32x4* st4 = (const u32x4*)(staging + (size_t)b * CAPB);
    for (int i = t; i < n / 2; i += 256) {
        u32x4 rr = __builtin_nontemporal_load(st4 + i);   // two records
#pragma unroll
        for (int q = 0; q < 2; ++q) {
            unsigned int key = q ? rr.z : rr.x;
            unsigned int vbits = q ? rr.w : rr.y;
            if (key != SENT) {
                int rl = (key >> 14) & 63;
                int p = atomicAdd(&lcnt[rl], 1);
                if (p < CAP) {
                    unsigned int col = key & 16383u;
                    __half hv = __float2half(__uint_as_float(vbits));
                    lbin[rl * CAP + p] = (col << 16) | (unsigned int)__half_as_ushort(hv);
                }
            }
        }
    }
    __syncthreads();
    if (t < 64) {                       // zero-pad each row bin to multiple of 8
        int c = lcnt[t];
        if (c > CAP) c = CAP;
        int lim = (c + 7) & ~7;
        for (int p = c; p < lim; ++p) lbin[t * CAP + p] = 0u;
        lcnt[t] = lim;
    }
    __syncthreads();
    int w = t >> 6;                     // wave 0..3
    int lane = t & 63;
    const unsigned int* xh = xh0 + (size_t)h * IN_F * 64;
    for (int rr = 0; rr < 16; ++rr) {
        int rl = w * 16 + rr;
        int o = b * 64 + rl;
        int nn = __builtin_amdgcn_readfirstlane(lcnt[rl]);
        float ax = 0.f, ay = 0.f;
        for (int j = 0; j < nn; j += 8) {
            uint4 ea = *(const uint4*)&lbin[rl * CAP + j];       // uniform addr -> broadcast
            uint4 eb = *(const uint4*)&lbin[rl * CAP + j + 4];
            unsigned int e[8];
            e[0] = __builtin_amdgcn_readfirstlane(ea.x);
            e[1] = __builtin_amdgcn_readfirstlane(ea.y);
            e[2] = __builtin_amdgcn_readfirstlane(ea.z);
            e[3] = __builtin_amdgcn_readfirstlane(ea.w);
            e[4] = __builtin_amdgcn_readfirstlane(eb.x);
            e[5] = __builtin_amdgcn_readfirstlane(eb.y);
            e[6] = __builtin_amdgcn_readfirstlane(eb.z);
            e[7] = __builtin_amdgcn_readfirstlane(eb.w);
            unsigned int g[8];
#pragma unroll
            for (int k = 0; k < 8; ++k) {
                const unsigned int* p = xh + ((e[k] >> 16) << 6);  // scalar base
                g[k] = p[lane];                                     // vgpr offset
            }
#pragma unroll
            for (int k = 0; k < 8; ++k) {
                float v = __half2float(__ushort_as_half((unsigned short)(e[k] & 0xffffu)));
                ax += __uint_as_float(g[k] << 16) * v;
                ay += __uint_as_float(g[k] & 0xffff0000u) * v;
            }
        }
        float bv = bias[o];
        unsigned long long wv = ((unsigned long long)__float_as_uint(ay + bv) << 32)
                              | __float_as_uint(ax + bv);
        __builtin_nontemporal_store(wv,
            (unsigned long long*)(outT + (size_t)o * 256 + h * 128 + 2 * lane));
    }
}

// ---------------- outT [OUT][256] -> out [256][OUT] ----------------

__global__ void transpose_out_kernel(const float* __restrict__ outT,
                                     float* __restrict__ out) {
    __shared__ float tile[64][65];
    int o0 = blockIdx.x * 64;
    int b0 = blockIdx.y * 64;
    int tx = threadIdx.x & 63;
    int ty = threadIdx.x >> 6;
#pragma unroll
    for (int k = 0; k < 64; k += 4)
        tile[ty + k][tx] =
            __builtin_nontemporal_load(&outT[(size_t)(o0 + ty + k) * BATCH_N + (b0 + tx)]);
    __syncthreads();
#pragma unroll
    for (int k = 0; k < 64; k += 4)
        __builtin_nontemporal_store(tile[tx][ty + k],
            &out[(size_t)(b0 + ty + k) * OUT_F + (o0 + tx)]);
}

extern "C" void kernel_launch(void* const* d_in, const int* in_sizes, int n_in,
                              void* d_out, int out_size, void* d_ws, size_t ws_size,
                              hipStream_t stream) {
    const float* x     = (const float*)d_in[0];
    const float* wvals = (const float*)d_in[1];
    const float* bias  = (const float*)d_in[2];
    const int*   rows  = (const int*)d_in[3];
    const int*   cols  = (const int*)d_in[4];
    float* out = (float*)d_out;
    int nnz = in_sizes[1];

    const size_t MB = 1024 * 1024;
    char* ws = (char*)d_ws;
    __hip_bfloat16* xTh = (__hip_bfloat16*)(ws);        // [0, 8 MB): [2][IN][128] bf16
    float* outT    = (float*)(ws + 8 * MB);             // [8, 24 MB): [OUT][256] fp32
    uint2* staging = (uint2*)(ws + 24 * MB);            // [24, 38 MB): [NBUCK][CAPB]
    int*   gcursor = (int*)(ws + 38 * MB);              // 1 KB

    hipMemsetAsync(gcursor, 0, NBUCK * sizeof(int), stream);

    int npart = (nnz + EPB - 1) / EPB;
    prep_kernel<<<TBLK + npart, 256, 0, stream>>>(x, xTh, rows, cols, wvals, nnz,
                                                  gcursor, staging);
    accum_kernel<<<NBUCK * 2, 256, 0, stream>>>((const unsigned int*)xTh, staging,
                                                gcursor, bias, outT);
    transpose_out_kernel<<<dim3(OUT_F / 64, BATCH_N / 64), 256, 0, stream>>>(outT, out);
}

// Round 12
// 144.004 us; speedup vs baseline: 1.2623x; 1.1916x over previous
//
#include <hip/hip_runtime.h>
#include <hip/hip_bf16.h>
#include <hip/hip_fp16.h>

#define BATCH_N 256
#define IN_F    16384
#define OUT_F   16384
#define CAP     128              // edge slots per row (mean 61, 8.6 sigma margin)
#define NBUCK   256              // coarse buckets: row >> 6, 64 rows each
#define CAPB    6656             // bucket staging capacity (mean ~5500 padded + margin)
#define EPB     2048             // edges per partition block (489 blocks)
#define TBLK    1024             // transpose blocks inside fused prep kernel
#define SENT    0xFFFFFFFFu      // staging pad sentinel

typedef unsigned int u32x4 __attribute__((ext_vector_type(4)));
typedef float f32x4 __attribute__((ext_vector_type(4)));

// ---------------- fused prep: transpose_x (blocks 0..1023) + partition ----------------
// staging record: x = (row<<14)|col  (SENT for pads), y = fp32 bits of val
// Per-(block,bucket) reservations rounded to 8 records = 64 B lines.

__global__ void prep_kernel(const float* __restrict__ x,
                            __hip_bfloat16* __restrict__ xTh,
                            const int* __restrict__ rows,
                            const int* __restrict__ cols,
                            const float* __restrict__ vals, int nnz,
                            int* __restrict__ gcursor,
                            uint2* __restrict__ staging) {
    __shared__ int smem[64 * 65];
    int t = threadIdx.x;
    if (blockIdx.x < TBLK) {
        // ---- transpose + bf16 quantize: x [256][IN] -> xTh [2][IN][128] ----
        float* tile = (float*)smem;        // [64][65]
        int bid = blockIdx.x;
        int i0 = (bid & 255) * 64;
        int b0 = (bid >> 8) * 64;
        int tx = t & 63, ty = t >> 6;
#pragma unroll
        for (int k = 0; k < 64; k += 4)
            tile[(ty + k) * 65 + tx] = x[(size_t)(b0 + ty + k) * IN_F + i0 + tx];
        __syncthreads();
        int h = b0 >> 7, j0 = b0 & 127;
#pragma unroll
        for (int k = 0; k < 64; k += 4) {
            int col = i0 + ty + k;
            xTh[((size_t)h * IN_F + col) * 128 + j0 + tx] =
                __float2bfloat16(tile[tx * 65 + ty + k]);
        }
    } else {
        // ---- partition 2048 edges into 256 coarse buckets ----
        int* hist = smem;
        int* base = smem + NBUCK;
        hist[t] = 0;
        __syncthreads();
        int i0 = (blockIdx.x - TBLK) * EPB;
        unsigned int pack[8], vb[8];
        int bk[8];
#pragma unroll
        for (int k = 0; k < 8; ++k) {
            int i = i0 + k * 256 + t;
            if (i < nnz) {
                int r = rows[i], c = cols[i];
                pack[k] = ((unsigned int)r << 14) | (unsigned int)c;
                vb[k] = __float_as_uint(vals[i]);
                bk[k] = r >> 6;
                atomicAdd(&hist[bk[k]], 1);
            } else bk[k] = -1;
        }
        __syncthreads();
        int hcnt = hist[t];
        int padded = (hcnt + 7) & ~7;          // 64 B granularity
        base[t] = (padded > 0) ? atomicAdd(&gcursor[t], padded) : 0;
        __syncthreads();
        hist[t] = 0;
        __syncthreads();
#pragma unroll
        for (int k = 0; k < 8; ++k) {
            if (bk[k] >= 0) {
                int p = base[bk[k]] + atomicAdd(&hist[bk[k]], 1);
                if (p < CAPB)
                    staging[(size_t)bk[k] * CAPB + p] = make_uint2(pack[k], vb[k]);
            }
        }
        __syncthreads();
        // sentinel-pad the tail of this block's run
        for (int p = hcnt; p < padded; ++p) {
            int idx = base[t] + p;
            if (idx < CAPB)
                staging[(size_t)t * CAPB + idx] = make_uint2(SENT, 0u);
        }
    }
}

// ---------------- phase B: within-bucket scatter to per-row bins ----------------
// Output record (4 B): (col << 16) | fp16(val). Row implied by bin.

__global__ void bucket_scatter_kernel(const uint2* __restrict__ staging,
                                      const int* __restrict__ gcursor,
                                      unsigned int* __restrict__ edges, // [OUT][CAP]
                                      int* __restrict__ counts) {
    __shared__ int lcnt[64];
    __shared__ unsigned int lbin[64 * CAP];   // 32 KB
    int b = blockIdx.x;
    int t = threadIdx.x;
    if (t < 64) lcnt[t] = 0;
    __syncthreads();
    int n = gcursor[b];                 // multiple of 8 (padded reservations)
    if (n > CAPB) n = CAPB;
    const u32x4* st4 = (const u32x4*)(staging + (size_t)b * CAPB);
    for (int i = t; i < n / 2; i += 256) {
        u32x4 rr = __builtin_nontemporal_load(st4 + i);   // two records
#pragma unroll
        for (int q = 0; q < 2; ++q) {
            unsigned int key = q ? rr.z : rr.x;
            unsigned int vbits = q ? rr.w : rr.y;
            if (key != SENT) {
                int rl = (key >> 14) & 63;
                int p = atomicAdd(&lcnt[rl], 1);
                if (p < CAP) {
                    unsigned int col = key & 16383u;
                    __half hv = __float2half(__uint_as_float(vbits));
                    lbin[rl * CAP + p] =
                        (col << 16) | (unsigned int)__half_as_ushort(hv);
                }
            }
        }
    }
    __syncthreads();
    if (t < 64) {
        int c = lcnt[t];
        if (c > CAP) c = CAP;
        counts[b * 64 + t] = (c + 7) & ~7;
    }
    unsigned int* dst = edges + (size_t)b * 64 * CAP;
    for (int i4 = t; i4 < 64 * CAP / 4; i4 += 256) {
        int i = i4 * 4;
        int row = i >> 7;            // CAP = 128
        int slot = i & (CAP - 1);
        int c = lcnt[row];
        if (c > CAP) c = CAP;
        int lim = (c + 15) & ~15;    // 64 B line granularity
        if (slot < lim) {
            u32x4 v;
            v.x = (slot + 0 < c) ? lbin[i + 0] : 0u;
            v.y = (slot + 1 < c) ? lbin[i + 1] : 0u;
            v.z = (slot + 2 < c) ? lbin[i + 2] : 0u;
            v.w = (slot + 3 < c) ? lbin[i + 3] : 0u;
            __builtin_nontemporal_store(v, (u32x4*)(dst + i));
        }
    }
}

// ---------------- accumulate + direct transposed output ----------------
// 2048 blocks: rowgroup = blk>>1 (16 rows), h = blk&1 (round-robin XCD dispatch
// keeps one 4 MB xh half per XCD L2). Wave w computes rows w*4..w*4+3 via the
// scalar edge-list path, parks 128-batch results in an LDS slab, then the
// block writes out[b][o0..o0+15] directly: 16 floats = one 64 B line per store.

__global__ void accum_kernel(const unsigned int* __restrict__ xh0, // [2][IN][64] bf162
                             const unsigned int* __restrict__ edges, // [OUT][CAP]
                             const int*   __restrict__ counts,    // multiple of 8
                             const float* __restrict__ bias,
                             float* __restrict__ out) {            // [256][OUT]
    __shared__ float slab[128][17];     // [batch_in_half][row_local], pad 17
    int blk = blockIdx.x;
    int h = blk & 1;
    int o0 = (blk >> 1) * 16;
    int w = threadIdx.x >> 6;           // wave 0..3
    int lane = threadIdx.x & 63;
    const unsigned int* xh = xh0 + (size_t)h * IN_F * 64;
#pragma unroll
    for (int rr = 0; rr < 4; ++rr) {
        int rl = w * 4 + rr;
        int o = __builtin_amdgcn_readfirstlane(o0 + rl);
        int n = counts[o];              // uniform
        const unsigned int* el = edges + (size_t)o * CAP;
        float ax = 0.f, ay = 0.f;
        for (int j = 0; j < n; j += 8) {
            unsigned int e[8];
#pragma unroll
            for (int k = 0; k < 8; ++k) e[k] = el[j + k];   // uniform -> s_load
            unsigned int g[8];
#pragma unroll
            for (int k = 0; k < 8; ++k) {
                const unsigned int* p = xh + ((e[k] >> 16) << 6);  // scalar base
                g[k] = p[lane];                                     // vgpr offset
            }
#pragma unroll
            for (int k = 0; k < 8; ++k) {
                float v = __half2float(__ushort_as_half((unsigned short)(e[k] & 0xffffu)));
                ax += __uint_as_float(g[k] << 16) * v;
                ay += __uint_as_float(g[k] & 0xffff0000u) * v;
            }
        }
        float bv = bias[o];
        slab[2 * lane + 0][rl] = ax + bv;   // batch 2t   of this half
        slab[2 * lane + 1][rl] = ay + bv;   // batch 2t+1
    }
    __syncthreads();
    // write phase: 512 float4 items (128 batches x 4 quarters), 2 per thread
#pragma unroll
    for (int it = 0; it < 2; ++it) {
        int item = threadIdx.x + it * 256;
        int bl = item >> 2;             // batch within half, 0..127
        int q = item & 3;               // quarter of 16 rows
        f32x4 v;
        v.x = slab[bl][q * 4 + 0];
        v.y = slab[bl][q * 4 + 1];
        v.z = slab[bl][q * 4 + 2];
        v.w = slab[bl][q * 4 + 3];
        __builtin_nontemporal_store(v,
            (f32x4*)(out + (size_t)(h * 128 + bl) * OUT_F + o0 + q * 4));
    }
}

extern "C" void kernel_launch(void* const* d_in, const int* in_sizes, int n_in,
                              void* d_out, int out_size, void* d_ws, size_t ws_size,
                              hipStream_t stream) {
    const float* x     = (const float*)d_in[0];
    const float* wvals = (const float*)d_in[1];
    const float* bias  = (const float*)d_in[2];
    const int*   rows  = (const int*)d_in[3];
    const int*   cols  = (const int*)d_in[4];
    float* out = (float*)d_out;
    int nnz = in_sizes[1];

    const size_t MB = 1024 * 1024;
    char* ws = (char*)d_ws;
    __hip_bfloat16* xTh = (__hip_bfloat16*)(ws);        // [0, 8 MB): [2][IN][128] bf16
    uint2* staging = (uint2*)(ws + 8 * MB);             // [8, 21.6 MB): [NBUCK][CAPB]
    unsigned int* edges = (unsigned int*)(ws + 22 * MB);// [22, 30 MB): [OUT][CAP] u32
    int*   gcursor = (int*)(ws + 30 * MB);              // 1 KB
    int*   counts  = (int*)(ws + 30 * MB + 4096);       // 64 KB

    (void)hipMemsetAsync(gcursor, 0, NBUCK * sizeof(int), stream);

    int npart = (nnz + EPB - 1) / EPB;
    prep_kernel<<<TBLK + npart, 256, 0, stream>>>(x, xTh, rows, cols, wvals, nnz,
                                                  gcursor, staging);
    bucket_scatter_kernel<<<NBUCK, 256, 0, stream>>>(staging, gcursor, edges, counts);
    accum_kernel<<<(OUT_F / 16) * 2, 256, 0, stream>>>((const unsigned int*)xTh, edges,
                                                       counts, bias, out);
}

// Round 13
// 141.169 us; speedup vs baseline: 1.2877x; 1.0201x over previous
//
#include <hip/hip_runtime.h>
#include <hip/hip_bf16.h>
#include <hip/hip_fp16.h>

#define BATCH_N 256
#define IN_F    16384
#define OUT_F   16384
#define CAP     128              // edge slots per row (mean 61, 8.6 sigma margin)
#define NBUCK   512              // coarse buckets: row >> 5, 32 rows each
#define CAPB    2560             // bucket staging capacity (mean 1953 + 13 sigma)
#define EPB     2048             // edges per partition block (489 blocks)
#define TBLK    1024             // transpose blocks inside fused prep kernel

typedef unsigned int u32x4 __attribute__((ext_vector_type(4)));
typedef float f32x4 __attribute__((ext_vector_type(4)));

// ---------------- fused prep: transpose_x (blocks 0..1023) + partition ----------------
// staging record: x = (row<<14)|col, y = fp32 bits of val. Exact reservations.

__global__ void prep_kernel(const float* __restrict__ x,
                            __hip_bfloat16* __restrict__ xTh,
                            const int* __restrict__ rows,
                            const int* __restrict__ cols,
                            const float* __restrict__ vals, int nnz,
                            int* __restrict__ gcursor,
                            uint2* __restrict__ staging) {
    __shared__ int smem[64 * 65];      // transpose tile / partition hist+base
    int t = threadIdx.x;
    if (blockIdx.x < TBLK) {
        // ---- transpose + bf16 quantize: x [256][IN] -> xTh [2][IN][128] ----
        float* tile = (float*)smem;        // [64][65]
        int bid = blockIdx.x;
        int i0 = (bid & 255) * 64;
        int b0 = (bid >> 8) * 64;
        int tx4 = t & 15;                  // float4 index within 64-col tile
        int r16 = t >> 4;                  // 0..15
#pragma unroll
        for (int k = 0; k < 4; ++k) {
            int row = r16 + k * 16;        // batch row within tile
            f32x4 v = *(const f32x4*)(x + (size_t)(b0 + row) * IN_F + i0 + tx4 * 4);
            tile[row * 65 + tx4 * 4 + 0] = v.x;
            tile[row * 65 + tx4 * 4 + 1] = v.y;
            tile[row * 65 + tx4 * 4 + 2] = v.z;
            tile[row * 65 + tx4 * 4 + 3] = v.w;
        }
        __syncthreads();
        int tx = t & 63, ty = t >> 6;
        int h = b0 >> 7, j0 = b0 & 127;
#pragma unroll
        for (int k = 0; k < 64; k += 4) {
            int col = i0 + ty + k;
            xTh[((size_t)h * IN_F + col) * 128 + j0 + tx] =
                __float2bfloat16(tile[tx * 65 + ty + k]);
        }
    } else {
        // ---- partition 2048 edges into 512 coarse buckets ----
        int* hist = smem;                  // [512]
        int* base = smem + NBUCK;          // [512]
        hist[t] = 0; hist[t + 256] = 0;
        __syncthreads();
        int i0 = (blockIdx.x - TBLK) * EPB;
        unsigned int pack[8], vb[8];
        int bk[8];
#pragma unroll
        for (int k = 0; k < 8; ++k) {
            int i = i0 + k * 256 + t;
            if (i < nnz) {
                int r = rows[i], c = cols[i];
                pack[k] = ((unsigned int)r << 14) | (unsigned int)c;
                vb[k] = __float_as_uint(vals[i]);
                bk[k] = r >> 5;
                atomicAdd(&hist[bk[k]], 1);
            } else bk[k] = -1;
        }
        __syncthreads();
#pragma unroll
        for (int q = 0; q < 2; ++q) {
            int bin = t + q * 256;
            int h = hist[bin];
            base[bin] = (h > 0) ? atomicAdd(&gcursor[bin], h) : 0;
        }
        __syncthreads();
        hist[t] = 0; hist[t + 256] = 0;
        __syncthreads();
#pragma unroll
        for (int k = 0; k < 8; ++k) {
            if (bk[k] >= 0) {
                int p = base[bk[k]] + atomicAdd(&hist[bk[k]], 1);
                if (p < CAPB)
                    staging[(size_t)bk[k] * CAPB + p] = make_uint2(pack[k], vb[k]);
            }
        }
    }
}

// ---------------- phase B: within-bucket scatter to per-row bins ----------------
// 512 blocks x 512 threads (2 blocks/CU, 16 waves/CU). Record (4 B):
// (col << 16) | fp16(val). Row implied by bin.

__global__ void __launch_bounds__(512)
bucket_scatter_kernel(const uint2* __restrict__ staging,
                      const int* __restrict__ gcursor,
                      unsigned int* __restrict__ edges, // [OUT][CAP]
                      int* __restrict__ counts) {
    __shared__ int lcnt[32];
    __shared__ unsigned int lbin[32 * CAP];   // 16 KB
    int b = blockIdx.x;
    int t = threadIdx.x;
    if (t < 32) lcnt[t] = 0;
    __syncthreads();
    int n = gcursor[b];
    if (n > CAPB) n = CAPB;
    const uint2* st = staging + (size_t)b * CAPB;
    for (int i = t; i < n; i += 512) {
        uint2 rec = __builtin_nontemporal_load((const unsigned long long*)st + i)
                        ? make_uint2(0, 0) : make_uint2(0, 0);  // placeholder
        (void)rec;
        uint2 r2;
        {
            unsigned long long v =
                __builtin_nontemporal_load((const unsigned long long*)st + i);
            r2.x = (unsigned int)(v & 0xffffffffull);
            r2.y = (unsigned int)(v >> 32);
        }
        int rl = (r2.x >> 14) & 31;
        int p = atomicAdd(&lcnt[rl], 1);
        if (p < CAP) {
            unsigned int col = r2.x & 16383u;
            __half hv = __float2half(__uint_as_float(r2.y));
            lbin[rl * CAP + p] = (col << 16) | (unsigned int)__half_as_ushort(hv);
        }
    }
    __syncthreads();
    if (t < 32) {
        int c = lcnt[t];
        if (c > CAP) c = CAP;
        counts[b * 32 + t] = (c + 7) & ~7;
    }
    unsigned int* dst = edges + (size_t)b * 32 * CAP;
    for (int i4 = t; i4 < 32 * CAP / 4; i4 += 512) {
        int i = i4 * 4;
        int row = i >> 7;            // CAP = 128
        int slot = i & (CAP - 1);
        int c = lcnt[row];
        if (c > CAP) c = CAP;
        int lim = (c + 7) & ~7;
        if (slot < lim) {
            u32x4 v;
            v.x = (slot + 0 < c) ? lbin[i + 0] : 0u;
            v.y = (slot + 1 < c) ? lbin[i + 1] : 0u;
            v.z = (slot + 2 < c) ? lbin[i + 2] : 0u;
            v.w = (slot + 3 < c) ? lbin[i + 3] : 0u;
            __builtin_nontemporal_store(v, (u32x4*)(dst + i));
        }
    }
}

// ---------------- accumulate + direct transposed output ----------------
// 2048 blocks: rowgroup = blk>>1 (16 rows), h = blk&1 (round-robin XCD dispatch
// keeps one 4 MB xh half per XCD L2). Scalar edge lists with software-pipelined
// s_load prefetch; LDS slab; final out written directly (64 B line per store).

__global__ void accum_kernel(const unsigned int* __restrict__ xh0, // [2][IN][64] bf162
                             const unsigned int* __restrict__ edges, // [OUT][CAP]
                             const int*   __restrict__ counts,    // multiple of 8
                             const float* __restrict__ bias,
                             float* __restrict__ out) {            // [256][OUT]
    __shared__ float slab[128][17];     // [batch_in_half][row_local], pad 17
    int blk = blockIdx.x;
    int h = blk & 1;
    int o0 = (blk >> 1) * 16;
    int w = threadIdx.x >> 6;           // wave 0..3
    int lane = threadIdx.x & 63;
    const unsigned int* xh = xh0 + (size_t)h * IN_F * 64;
#pragma unroll
    for (int rr = 0; rr < 4; ++rr) {
        int rl = w * 4 + rr;
        int o = __builtin_amdgcn_readfirstlane(o0 + rl);
        int n = counts[o];              // uniform
        const u32x4* el4 = (const u32x4*)(edges + (size_t)o * CAP);
        float ax = 0.f, ay = 0.f;
        u32x4 ca = el4[0], cb = el4[1];
        for (int j = 0; j < n; j += 8) {
            u32x4 na = el4[(j >> 2) + 2];      // prefetch next chunk (may overread
            u32x4 nb = el4[(j >> 2) + 3];      //  <=32 B past row; region mapped)
            unsigned int e[8];
            e[0] = ca.x; e[1] = ca.y; e[2] = ca.z; e[3] = ca.w;
            e[4] = cb.x; e[5] = cb.y; e[6] = cb.z; e[7] = cb.w;
            unsigned int g[8];
#pragma unroll
            for (int k = 0; k < 8; ++k) {
                const unsigned int* p = xh + ((e[k] >> 16) << 6);  // scalar base
                g[k] = p[lane];                                     // vgpr offset
            }
#pragma unroll
            for (int k = 0; k < 8; ++k) {
                float v = __half2float(__ushort_as_half((unsigned short)(e[k] & 0xffffu)));
                ax += __uint_as_float(g[k] << 16) * v;
                ay += __uint_as_float(g[k] & 0xffff0000u) * v;
            }
            ca = na; cb = nb;
        }
        float bv = bias[o];
        slab[2 * lane + 0][rl] = ax + bv;   // batch 2t   of this half
        slab[2 * lane + 1][rl] = ay + bv;   // batch 2t+1
    }
    __syncthreads();
    // write phase: 512 float4 items (128 batches x 4 quarters), 2 per thread
#pragma unroll
    for (int it = 0; it < 2; ++it) {
        int item = threadIdx.x + it * 256;
        int bl = item >> 2;             // batch within half, 0..127
        int q = item & 3;               // quarter of 16 rows
        f32x4 v;
        v.x = slab[bl][q * 4 + 0];
        v.y = slab[bl][q * 4 + 1];
        v.z = slab[bl][q * 4 + 2];
        v.w = slab[bl][q * 4 + 3];
        __builtin_nontemporal_store(v,
            (f32x4*)(out + (size_t)(h * 128 + bl) * OUT_F + o0 + q * 4));
    }
}

extern "C" void kernel_launch(void* const* d_in, const int* in_sizes, int n_in,
                              void* d_out, int out_size, void* d_ws, size_t ws_size,
                              hipStream_t stream) {
    const float* x     = (const float*)d_in[0];
    const float* wvals = (const float*)d_in[1];
    const float* bias  = (const float*)d_in[2];
    const int*   rows  = (const int*)d_in[3];
    const int*   cols  = (const int*)d_in[4];
    float* out = (float*)d_out;
    int nnz = in_sizes[1];

    const size_t MB = 1024 * 1024;
    char* ws = (char*)d_ws;
    __hip_bfloat16* xTh = (__hip_bfloat16*)(ws);        // [0, 8 MB): [2][IN][128] bf16
    uint2* staging = (uint2*)(ws + 8 * MB);             // [8, 18.5 MB): [NBUCK][CAPB]
    unsigned int* edges = (unsigned int*)(ws + 22 * MB);// [22, 30 MB): [OUT][CAP] u32
    int*   gcursor = (int*)(ws + 30 * MB);              // 2 KB
    int*   counts  = (int*)(ws + 30 * MB + 4096);       // 64 KB

    (void)hipMemsetAsync(gcursor, 0, NBUCK * sizeof(int), stream);

    int npart = (nnz + EPB - 1) / EPB;
    prep_kernel<<<TBLK + npart, 256, 0, stream>>>(x, xTh, rows, cols, wvals, nnz,
                                                  gcursor, staging);
    bucket_scatter_kernel<<<NBUCK, 512, 0, stream>>>(staging, gcursor, edges, counts);
    accum_kernel<<<(OUT_F / 16) * 2, 256, 0, stream>>>((const unsigned int*)xTh, edges,
                                                       counts, bias, out);
}